// Round 13
// baseline (349.339 us; speedup 1.0000x reference)
//
#include <hip/hip_runtime.h>

#define NN    16384
#define HD    128
#define G4    512
#define KST   16
#define NRELS 3
#define NPB   32   // nodes per lstm block (2 row-tiles of 16)
#define LOG2E 1.44269504f

using f16x8 = __attribute__((ext_vector_type(8))) _Float16;
using f32x4 = __attribute__((ext_vector_type(4))) float;

typedef __attribute__((address_space(3))) unsigned       lds_u32_t;
typedef __attribute__((address_space(1))) const unsigned glb_u32_t;
// one dword per lane: global addr per-lane, LDS dest = base + lane*4
#define GLOAD_LDS(gp, lp) \
    __builtin_amdgcn_global_load_lds((glb_u32_t*)(const void*)(gp), \
                                     (lds_u32_t*)(void*)(lp), 4, 0, 0)

static __device__ __forceinline__ f32x4 f4splat(float v) {
    f32x4 r; r[0] = v; r[1] = v; r[2] = v; r[3] = v; return r;
}
static __device__ __forceinline__ f16x8 load8h(const float* p) {
    const float4 a = ((const float4*)p)[0];
    const float4 b = ((const float4*)p)[1];
    f16x8 r;
    r[0] = (_Float16)a.x; r[1] = (_Float16)a.y; r[2] = (_Float16)a.z; r[3] = (_Float16)a.w;
    r[4] = (_Float16)b.x; r[5] = (_Float16)b.y; r[6] = (_Float16)b.z; r[7] = (_Float16)b.w;
    return r;
}
static __device__ __forceinline__ f16x8 load8h_l2e(const float* p) {
    const float4 a = ((const float4*)p)[0];
    const float4 b = ((const float4*)p)[1];
    f16x8 r;
    r[0] = (_Float16)(a.x * LOG2E); r[1] = (_Float16)(a.y * LOG2E);
    r[2] = (_Float16)(a.z * LOG2E); r[3] = (_Float16)(a.w * LOG2E);
    r[4] = (_Float16)(b.x * LOG2E); r[5] = (_Float16)(b.y * LOG2E);
    r[6] = (_Float16)(b.z * LOG2E); r[7] = (_Float16)(b.w * LOG2E);
    return r;
}
static __device__ __forceinline__ f32x4 mfma16h(f16x8 a, f16x8 b, f32x4 c) {
    return __builtin_amdgcn_mfma_f32_16x16x32_f16(a, b, c, 0, 0, 0);
}
static __device__ __forceinline__ unsigned short f2h_bits(float f) {
    return __builtin_bit_cast(unsigned short, (_Float16)f);
}
static __device__ __forceinline__ float h2f(unsigned short b) {
    return (float)__builtin_bit_cast(_Float16, b);
}
// inputs PRE-SCALED by log2e -> bare v_exp2 with free neg modifier
static __device__ __forceinline__ float sigm2(float x) {
    return __builtin_amdgcn_rcpf(1.0f + __builtin_amdgcn_exp2f(-x));
}
static __device__ __forceinline__ float tanh2p(float x) {
    return 2.0f * __builtin_amdgcn_rcpf(1.0f + __builtin_amdgcn_exp2f(-2.0f * x)) - 1.0f;
}
static __device__ __forceinline__ float tanhn(float x) {
    return 2.0f * __builtin_amdgcn_rcpf(1.0f + __builtin_amdgcn_exp2f(-2.8853901f * x)) - 1.0f;
}
static __device__ __forceinline__ void barrier_lgkm() {
    asm volatile("s_waitcnt lgkmcnt(0)" ::: "memory");
    __builtin_amdgcn_s_barrier();
}

// ---------------------------------------------------------------------------
// C[row,col] = A[row,:] @ W[r][col,:]^T (+bias[r][col]); fp16 inputs, f32 acc.
// MODE 0: f32 out [row*OUTC+col]               (tc = conn @ trans.T)
// MODE 1: fp16*log2e, split gate-pair planes:  (xW, DMA-gatherable)
//   plane (q>>1): u16[((plane*3*NN + r*NN + row)*128 + (col&127))*2 + (q&1)]
//   i.e. plane0 = (i,f) dword per (r,row,hidcol), plane1 = (g,o) dword.
// ---------------------------------------------------------------------------
template <int OUTC, int MODE>
__global__ __launch_bounds__(512, 2) void gemm_rt(
    const float* __restrict__ A, const float* __restrict__ W,
    const float* __restrict__ bias, void* __restrict__ outp)
{
    constexpr int CW = OUTC / 8;
    constexpr int CT = CW / 16;
    const int tid = threadIdx.x;
    const int w = tid >> 6, lane = tid & 63;
    const int g = lane >> 4, m = lane & 15;
    const int n0 = blockIdx.x * 64;
    const int r = blockIdx.y;
    const float* Wr = W + (size_t)r * OUTC * HD;

    f32x4 acc[4][CT];
#pragma unroll
    for (int rt = 0; rt < 4; ++rt)
#pragma unroll
        for (int ct = 0; ct < CT; ++ct) acc[rt][ct] = f4splat(0.0f);

#pragma unroll
    for (int kc = 0; kc < 4; ++kc) {
        f16x8 a[4];
#pragma unroll
        for (int rt = 0; rt < 4; ++rt)
            a[rt] = load8h(A + (size_t)(n0 + rt * 16 + m) * HD + kc * 32 + 8 * g);
        f16x8 b[CT];
#pragma unroll
        for (int ct = 0; ct < CT; ++ct)
            b[ct] = load8h(Wr + (size_t)(w * CW + ct * 16 + m) * HD + kc * 32 + 8 * g);
#pragma unroll
        for (int rt = 0; rt < 4; ++rt)
#pragma unroll
            for (int ct = 0; ct < CT; ++ct)
                acc[rt][ct] = mfma16h(a[rt], b[ct], acc[rt][ct]);
    }

#pragma unroll
    for (int rt = 0; rt < 4; ++rt)
#pragma unroll
        for (int ct = 0; ct < CT; ++ct) {
            const int col = w * CW + ct * 16 + m;
            const float bv = bias ? bias[r * OUTC + col] : 0.0f;
#pragma unroll
            for (int e = 0; e < 4; ++e) {
                const int row = n0 + rt * 16 + 4 * g + e;
                const float v = acc[rt][ct][e] + bv;
                if constexpr (MODE == 0) {
                    ((float*)outp)[(size_t)row * OUTC + col] = v;
                } else {
                    const int hc = col & 127, q = col >> 7;
                    const size_t off =
                        (((size_t)(q >> 1) * NRELS * NN + (size_t)r * NN + row) * HD + hc) * 2 + (q & 1);
                    ((unsigned short*)outp)[off] = f2h_bits(v * LOG2E);
                }
            }
        }
}

// ---------------------------------------------------------------------------
// NPB=32, 2x work/wave at 4 waves/SIMD. 8 waves; wave w owns hidden cols
// w*16+m of all 4 gate quads for BOTH 16-node row-tiles (Whh frags = 64 VGPR).
// Gather has ZERO VGPR footprint: 16 global_load_lds dwords/wave/step DMA the
// (i,f) and (g,o) pairs straight into a SINGLE-buffered xbuf (each wave reads
// only its own DMA region -> no barrier/ds_write needed; wave-local vmcnt(0)
// at step top, lgkmcnt(0) before refill). h dbuf XOR-swizzled, 1 barrier/step.
// ---------------------------------------------------------------------------
__global__ __launch_bounds__(512, 4) void lstm_kernel(
    const float* __restrict__ x, const int* __restrict__ nbr,
    const float* __restrict__ Whh, const float* __restrict__ fcs,
    const float* __restrict__ fcn, const float* __restrict__ bias,
    const unsigned short* __restrict__ xW, float* __restrict__ Xout)
{
    __shared__ unsigned xb_if[64 * 64];             // [w*8+rt*4+e][lane], 16 KB
    __shared__ unsigned xb_go[64 * 64];             // 16 KB
    __shared__ unsigned short h_lds[2][NPB * HD];   // fp16, swizzled, dbuf 16 KB
    __shared__ int idx_lds[KST * NPB];              // [t][n], idx<<9, 2 KB

    const int tid = threadIdx.x;
    const int w = tid >> 6, lane = tid & 63;
    const int g = lane >> 4, m = lane & 15;
    const int n0 = blockIdx.x * NPB;
    const int r = blockIdx.y;
    const char* pif = (const char*)xW + (size_t)r * NN * 512;
    const char* pgo = pif + (size_t)NRELS * NN * 512;
    const unsigned lane4 = (unsigned)(w * 16 + m) * 4u;

    // anti-phase-lock: offset the (x, x+256) co-resident pair by ~half a step
    if ((blockIdx.x >> 8) & 1) {
        asm volatile("s_sleep 32");
        asm volatile("s_sleep 22");
    }

    {   // idx table [t][n], pre-shifted (512 B per node-row per plane)
        const int t = tid >> 5, n = tid & 31;
        idx_lds[tid] = nbr[((size_t)r * NN + n0 + n) * KST + t] << 9;
    }

    // Whh B-fragments (x log2e): gate cols q*128 + w*16 + m, resident
    f16x8 bw[4][4];
    const float* whr = Whh + (size_t)r * G4 * HD;
#pragma unroll
    for (int q = 0; q < 4; ++q)
#pragma unroll
        for (int kc = 0; kc < 4; ++kc)
            bw[q][kc] = load8h_l2e(whr + (size_t)(q * 128 + w * 16 + m) * HD + kc * 32 + 8 * g);

    // step-invariant LDS offsets (ushort units); rt adds +2048 imm
    int rd_off[4], wr_off[4];
#pragma unroll
    for (int kc = 0; kc < 4; ++kc)
        rd_off[kc] = m * HD + ((kc * 32 + 8 * g) ^ ((m & 7) << 3));
#pragma unroll
    for (int e = 0; e < 4; ++e) {
        const int row = 4 * g + e;
        wr_off[e] = row * HD + ((w * 16 + m) ^ ((row & 7) << 3));
    }
    const int xbb = (w << 9) + lane;   // per-lane xbuf dword base; + (rt*4+e)<<6 imm

    float cst[2][4] = {{0.f, 0.f, 0.f, 0.f}, {0.f, 0.f, 0.f, 0.f}};
    __syncthreads();   // idx_lds ready

#define ISSUE_DMA(tt)                                                          \
    do {                                                                       \
        _Pragma("unroll")                                                      \
        for (int rt = 0; rt < 2; ++rt) {                                       \
            const int4 i4 = *(const int4*)&idx_lds[(tt) * 32 + rt * 16 + 4 * g]; \
            const unsigned o[4] = {(unsigned)i4.x, (unsigned)i4.y,             \
                                   (unsigned)i4.z, (unsigned)i4.w};            \
            _Pragma("unroll")                                                  \
            for (int e = 0; e < 4; ++e) {                                      \
                GLOAD_LDS(pif + o[e] + lane4, &xb_if[(w * 8 + rt * 4 + e) * 64]); \
                GLOAD_LDS(pgo + o[e] + lane4, &xb_go[(w * 8 + rt * 4 + e) * 64]); \
            }                                                                  \
        }                                                                      \
    } while (0)

    ISSUE_DMA(0);

    for (int t = 0; t < KST; ++t) {
        const int rb = t & 1;        // h read buffer
        const int wb = rb ^ 1;

        // this wave's DMA landed (wave-local; nothing else in flight)
        asm volatile("s_waitcnt vmcnt(0)" ::: "memory");

        f32x4 acc[2][4];
#pragma unroll
        for (int rt = 0; rt < 2; ++rt)
#pragma unroll
            for (int e = 0; e < 4; ++e) {
                const unsigned dif = xb_if[xbb + ((rt * 4 + e) << 6)];
                const unsigned dgo = xb_go[xbb + ((rt * 4 + e) << 6)];
                acc[rt][0][e] = h2f((unsigned short)(dif & 0xffffu));
                acc[rt][1][e] = h2f((unsigned short)(dif >> 16));
                acc[rt][2][e] = h2f((unsigned short)(dgo & 0xffffu));
                acc[rt][3][e] = h2f((unsigned short)(dgo >> 16));
            }
        // xbuf reads complete -> safe to refill the same region for t+1
        asm volatile("s_waitcnt lgkmcnt(0)" ::: "memory");
        if (t + 1 < KST) ISSUE_DMA(t + 1);

        __builtin_amdgcn_s_setprio(1);
        if (t > 0) {
            const unsigned short* hb = h_lds[rb];
#pragma unroll
            for (int kc = 0; kc < 4; ++kc) {
                f16x8 a[2];
#pragma unroll
                for (int rt = 0; rt < 2; ++rt)
                    a[rt] = *(const f16x8*)&hb[rd_off[kc] + rt * 2048];
#pragma unroll
                for (int rt = 0; rt < 2; ++rt)
#pragma unroll
                    for (int q = 0; q < 4; ++q)
                        acc[rt][q] = mfma16h(a[rt], bw[q][kc], acc[rt][q]);
            }
        }
        __builtin_amdgcn_s_setprio(0);

        // elementwise LSTM cell (i,f,g,o) in exp2 algebra; h -> other buffer
        unsigned short* nh = h_lds[wb];
#pragma unroll
        for (int rt = 0; rt < 2; ++rt)
#pragma unroll
            for (int e = 0; e < 4; ++e) {
                const float iv = sigm2(acc[rt][0][e]);
                const float fv = sigm2(acc[rt][1][e]);
                const float gv = tanh2p(acc[rt][2][e]);
                const float ov = sigm2(acc[rt][3][e]);
                const float cn = fv * cst[rt][e] + iv * gv;
                cst[rt][e] = cn;
                nh[wr_off[e] + rt * 2048] = f2h_bits(ov * tanhn(cn));
            }
        barrier_lgkm();   // h(t) visible for next step's MFMA
    }
#undef ISSUE_DMA

    // ---- FC + leaky-relu: wave w -> out cols w*16+m, 32 nodes. h in buf[0].
    {
        const unsigned short* hb = h_lds[0];
        const float* fsr = fcs + (size_t)r * HD * HD;
        const float* fnr = fcn + (size_t)r * HD * HD;
        const int col = w * 16 + m;
        f32x4 oacc[2];
        oacc[0] = f4splat(bias[r * HD + col]);
        oacc[1] = oacc[0];
#pragma unroll
        for (int kc = 0; kc < 4; ++kc) {
            const f16x8 bs = load8h(fsr + (size_t)col * HD + kc * 32 + 8 * g);
            const f16x8 bn = load8h(fnr + (size_t)col * HD + kc * 32 + 8 * g);
#pragma unroll
            for (int rt = 0; rt < 2; ++rt) {
                const f16x8 ax = load8h(x + (size_t)(n0 + rt * 16 + m) * HD + kc * 32 + 8 * g);
                const f16x8 ah = *(const f16x8*)&hb[rd_off[kc] + rt * 2048];
                oacc[rt] = mfma16h(ax, bs, oacc[rt]);
                oacc[rt] = mfma16h(ah, bn, oacc[rt]);
            }
        }
#pragma unroll
        for (int rt = 0; rt < 2; ++rt)
#pragma unroll
            for (int e = 0; e < 4; ++e) {
                const int row = rt * 16 + 4 * g + e;
                float v = oacc[rt][e];
                v = v > 0.0f ? v : 0.01f * v;
                Xout[((size_t)(n0 + row) * NRELS + r) * HD + col] = v;
            }
    }
}

// ---------------------------------------------------------------------------
// attention: one wave per node; softmax over 3 relations, f32 throughout
// ---------------------------------------------------------------------------
__global__ __launch_bounds__(256) void attn_kernel(
    const float* __restrict__ X, const float* __restrict__ tc,
    float* __restrict__ out)
{
    const int wv = blockIdx.x * (blockDim.x >> 6) + (threadIdx.x >> 6);
    const int lane = threadIdx.x & 63;
    if (wv >= NN) return;
    const size_t nb = (size_t)wv;

    const float t0 = tc[nb * HD + lane];
    const float t1 = tc[nb * HD + 64 + lane];
    float x0[3], x1[3], sc[3];
#pragma unroll
    for (int r = 0; r < 3; ++r) {
        x0[r] = X[(nb * 3 + r) * HD + lane];
        x1[r] = X[(nb * 3 + r) * HD + 64 + lane];
        float p = x0[r] * t0 + x1[r] * t1;
#pragma unroll
        for (int off = 32; off >= 1; off >>= 1)
            p += __shfl_xor(p, off, 64);
        sc[r] = p;
    }
    const float mx = fmaxf(sc[0], fmaxf(sc[1], sc[2]));
    const float e0 = __expf(sc[0] - mx), e1 = __expf(sc[1] - mx), e2 = __expf(sc[2] - mx);
    const float inv = __builtin_amdgcn_rcpf(e0 + e1 + e2);
    const float a0 = e0 * inv, a1 = e1 * inv, a2 = e2 * inv;
    out[nb * HD + lane]      = a0 * x0[0] + a1 * x0[1] + a2 * x0[2];
    out[nb * HD + 64 + lane] = a0 * x1[0] + a1 * x1[1] + a2 * x1[2];
}

extern "C" void kernel_launch(void* const* d_in, const int* in_sizes, int n_in,
                              void* d_out, int out_size, void* d_ws, size_t ws_size,
                              hipStream_t stream)
{
    const float* x     = (const float*)d_in[0];
    const float* conn  = (const float*)d_in[1];
    const int*   nbr   = (const int*)d_in[2];
    const float* trans = (const float*)d_in[3];
    const float* Wih   = (const float*)d_in[4];
    const float* Whh   = (const float*)d_in[5];
    const float* blstm = (const float*)d_in[6];
    const float* fcs   = (const float*)d_in[7];
    const float* fcn   = (const float*)d_in[8];
    const float* bias  = (const float*)d_in[9];
    float* out = (float*)d_out;

    // ws: xW planes fp16 2x[3][N][128]x2B | tc f32 [N][128] | X f32 [N][3][128]
    const size_t XW_B = (size_t)NRELS * NN * G4 * 2;   //  50.3 MB (both planes)
    const size_t TC_B = (size_t)NN * HD * 4;           //   8.4 MB
    const size_t XO_B = (size_t)NN * NRELS * HD * 4;   //  25.2 MB
    if (ws_size < XW_B + TC_B + XO_B) return;          //  83.9 MB floor

    char* wsb = (char*)d_ws;
    unsigned short* xW = (unsigned short*)wsb;
    float*          tc = (float*)(wsb + XW_B);
    float*          Xo = (float*)(wsb + XW_B + TC_B);

    gemm_rt<512, 1><<<dim3(NN / 64, NRELS), 512, 0, stream>>>(x, Wih, blstm, (void*)xW);
    gemm_rt<128, 0><<<dim3(NN / 64, 1), 512, 0, stream>>>(conn, trans, nullptr, (void*)tc);
    lstm_kernel<<<dim3(NN / NPB, NRELS), 512, 0, stream>>>(x, nbr, Whh, fcs, fcn, bias, xW, Xo);
    attn_kernel<<<dim3(NN / 4), 256, 0, stream>>>(Xo, tc, out);
}

// Round 14
// 313.012 us; speedup vs baseline: 1.1161x; 1.1161x over previous
//
#include <hip/hip_runtime.h>

#define NN    16384
#define HD    128
#define G4    512
#define KST   16
#define NRELS 3
#define NPB   16   // nodes per lstm block
#define LOG2E 1.44269504f
#define TT    2.8853901f   // 2*log2(e)

using f16x8 = __attribute__((ext_vector_type(8))) _Float16;
using f32x4 = __attribute__((ext_vector_type(4))) float;

static __device__ __forceinline__ f32x4 f4splat(float v) {
    f32x4 r; r[0] = v; r[1] = v; r[2] = v; r[3] = v; return r;
}
static __device__ __forceinline__ f16x8 load8h(const float* p) {
    const float4 a = ((const float4*)p)[0];
    const float4 b = ((const float4*)p)[1];
    f16x8 r;
    r[0] = (_Float16)a.x; r[1] = (_Float16)a.y; r[2] = (_Float16)a.z; r[3] = (_Float16)a.w;
    r[4] = (_Float16)b.x; r[5] = (_Float16)b.y; r[6] = (_Float16)b.z; r[7] = (_Float16)b.w;
    return r;
}
// load 8 f32, scale by s, convert fp16 (pre-scaled gate algebra)
static __device__ __forceinline__ f16x8 load8hs(const float* p, float s) {
    const float4 a = ((const float4*)p)[0];
    const float4 b = ((const float4*)p)[1];
    f16x8 r;
    r[0] = (_Float16)(a.x * s); r[1] = (_Float16)(a.y * s);
    r[2] = (_Float16)(a.z * s); r[3] = (_Float16)(a.w * s);
    r[4] = (_Float16)(b.x * s); r[5] = (_Float16)(b.y * s);
    r[6] = (_Float16)(b.z * s); r[7] = (_Float16)(b.w * s);
    return r;
}
static __device__ __forceinline__ f32x4 mfma16h(f16x8 a, f16x8 b, f32x4 c) {
    return __builtin_amdgcn_mfma_f32_16x16x32_f16(a, b, c, 0, 0, 0);
}
static __device__ __forceinline__ unsigned short f2h_bits(float f) {
    return __builtin_bit_cast(unsigned short, (_Float16)f);
}
static __device__ __forceinline__ float h2f(unsigned short b) {
    return (float)__builtin_bit_cast(_Float16, b);
}
static __device__ __forceinline__ void barrier_lgkm() {
    asm volatile("s_waitcnt lgkmcnt(0)" ::: "memory");
    __builtin_amdgcn_s_barrier();
}

// ---------------------------------------------------------------------------
// C[row,col] = A[row,:] @ W[r][col,:]^T (+bias[r][col]); fp16 inputs, f32 acc.
// MODE 0: f32 out [row*OUTC+col]            (tc = conn @ trans.T)
// MODE 1: fp16 out, gate-quad packed, pre-scaled: quads i,f,o x log2e,
//         quad g x 2*log2e (so cell uses bare exp2 with free neg modifier).
//         quad offset = (r*NN+row)*512 + (col&127)*4 + (col>>7)
// ---------------------------------------------------------------------------
template <int OUTC, int MODE>
__global__ __launch_bounds__(512, 2) void gemm_rt(
    const float* __restrict__ A, const float* __restrict__ W,
    const float* __restrict__ bias, void* __restrict__ outp)
{
    constexpr int CW = OUTC / 8;
    constexpr int CT = CW / 16;
    const int tid = threadIdx.x;
    const int w = tid >> 6, lane = tid & 63;
    const int g = lane >> 4, m = lane & 15;
    const int n0 = blockIdx.x * 64;
    const int r = blockIdx.y;
    const float* Wr = W + (size_t)r * OUTC * HD;

    f32x4 acc[4][CT];
#pragma unroll
    for (int rt = 0; rt < 4; ++rt)
#pragma unroll
        for (int ct = 0; ct < CT; ++ct) acc[rt][ct] = f4splat(0.0f);

#pragma unroll
    for (int kc = 0; kc < 4; ++kc) {
        f16x8 a[4];
#pragma unroll
        for (int rt = 0; rt < 4; ++rt)
            a[rt] = load8h(A + (size_t)(n0 + rt * 16 + m) * HD + kc * 32 + 8 * g);
        f16x8 b[CT];
#pragma unroll
        for (int ct = 0; ct < CT; ++ct)
            b[ct] = load8h(Wr + (size_t)(w * CW + ct * 16 + m) * HD + kc * 32 + 8 * g);
#pragma unroll
        for (int rt = 0; rt < 4; ++rt)
#pragma unroll
            for (int ct = 0; ct < CT; ++ct)
                acc[rt][ct] = mfma16h(a[rt], b[ct], acc[rt][ct]);
    }

#pragma unroll
    for (int rt = 0; rt < 4; ++rt)
#pragma unroll
        for (int ct = 0; ct < CT; ++ct) {
            const int col = w * CW + ct * 16 + m;
            const float bv = bias ? bias[r * OUTC + col] : 0.0f;
#pragma unroll
            for (int e = 0; e < 4; ++e) {
                const int row = n0 + rt * 16 + 4 * g + e;
                const float v = acc[rt][ct][e] + bv;
                if constexpr (MODE == 0) {
                    ((float*)outp)[(size_t)row * OUTC + col] = v;
                } else {
                    const int q = col >> 7;
                    const float s = (q == 2) ? 2.0f * LOG2E : LOG2E;
                    ((unsigned short*)outp)[((size_t)r * NN + row) * G4 + (size_t)(col & 127) * 4 + q] =
                        f2h_bits(v * s);
                }
            }
        }
}

// ---------------------------------------------------------------------------
// R12 structure (best measured: 271 us) + rcp-fused LSTM cell.
// 16 nodes/block, one relation. 8 waves; wave w owns hidden cols w*16+m for
// all 4 gate quads (Whh frags pre-scaled, 64 VGPRs, resident). Coalesced
// 2-deep gather staging via xbuf; one lgkm-only barrier/step; h dbuf
// XOR-swizzled; anti-phase-lock stagger for the (i, i+256) resident pair.
// Cell algebra: all gates as ratios over common denominators -> 5 exp2 +
// 2 rcp per element (was 5+5). c carried pre-scaled by 2*log2e.
// ---------------------------------------------------------------------------
__global__ __launch_bounds__(512, 4) void lstm_kernel(
    const float* __restrict__ x, const int* __restrict__ nbr,
    const float* __restrict__ Whh, const float* __restrict__ fcs,
    const float* __restrict__ fcn, const float* __restrict__ bias,
    const unsigned short* __restrict__ xW, float* __restrict__ Xout)
{
    __shared__ unsigned short h_lds[2][NPB * HD];   // fp16, swizzled, dbuf
    __shared__ unsigned short xbuf[2][NPB * G4];    // gathered quad rows, dbuf
    __shared__ int idx_lds[KST * NPB];              // [t][node], idx<<10

    const int tid = threadIdx.x;
    const int w = tid >> 6, lane = tid & 63;
    const int g = lane >> 4, m = lane & 15;
    const int n0 = blockIdx.x * NPB;
    const int r = blockIdx.y;
    const char* xwr = (const char*)(xW + (size_t)r * NN * G4);

    // anti-phase-lock: offset the (i, i+256) co-resident pair by ~half a step
    if ((blockIdx.x >> 8) & 1) {
        asm volatile("s_sleep 32");
        asm volatile("s_sleep 22");
    }

    if (tid < KST * NPB) {
        const int t = tid >> 4, n = tid & 15;
        idx_lds[tid] = nbr[((size_t)r * NN + n0 + n) * KST + t] << 10;
    }

    // Whh B-fragments: quads i,f,o x log2e; quad g x 2*log2e
    f16x8 bw[4][4];
    const float* whr = Whh + (size_t)r * G4 * HD;
#pragma unroll
    for (int q = 0; q < 4; ++q) {
        const float s = (q == 2) ? 2.0f * LOG2E : LOG2E;
#pragma unroll
        for (int kc = 0; kc < 4; ++kc)
            bw[q][kc] = load8hs(whr + (size_t)(q * 128 + w * 16 + m) * HD + kc * 32 + 8 * g, s);
    }

    // step-invariant offsets
    int rd_off[4], wr_off[4];
#pragma unroll
    for (int kc = 0; kc < 4; ++kc)
        rd_off[kc] = m * HD + ((kc * 32 + 8 * g) ^ ((m & 7) << 3));
#pragma unroll
    for (int e = 0; e < 4; ++e) {
        const int row = 4 * g + e;
        wr_off[e] = row * HD + ((w * 16 + m) ^ ((row & 7) << 3));
    }
    const int xb_wrA = (2 * w) * G4 + lane * 8;        // ushort units, 16B/lane
    const int xb_wrB = (2 * w + 1) * G4 + lane * 8;
    const int xb_rd  = (4 * g) * G4 + (w * 16 + m) * 4; // +e*G4 imm per element

    float cst[4] = {0.0f, 0.0f, 0.0f, 0.0f};   // 2*log2e * c
    __syncthreads();   // idx_lds ready

    // prologue: t=0 gather -> xbuf[0]; t=1 gather left in flight
    uint4 pa, pb;
    {
        const unsigned oa = (unsigned)idx_lds[0 * 16 + 2 * w];
        const unsigned ob = (unsigned)idx_lds[0 * 16 + 2 * w + 1];
        pa = *(const uint4*)(xwr + oa + lane * 16);
        pb = *(const uint4*)(xwr + ob + lane * 16);
        *(uint4*)&xbuf[0][xb_wrA] = pa;
        *(uint4*)&xbuf[0][xb_wrB] = pb;
        const unsigned oa1 = (unsigned)idx_lds[1 * 16 + 2 * w];
        const unsigned ob1 = (unsigned)idx_lds[1 * 16 + 2 * w + 1];
        pa = *(const uint4*)(xwr + oa1 + lane * 16);
        pb = *(const uint4*)(xwr + ob1 + lane * 16);
    }
    barrier_lgkm();

    for (int t = 0; t < KST; ++t) {
        const int rb = t & 1;        // xbuf/h read buffer
        const int wb = rb ^ 1;

        // quads for step t from xbuf (written at t-1, barrier'd)
        ushort4 xv[4];
#pragma unroll
        for (int e = 0; e < 4; ++e)
            xv[e] = *(const ushort4*)&xbuf[rb][xb_rd + e * G4];

        f32x4 acc[4];
#pragma unroll
        for (int e = 0; e < 4; ++e) {
            acc[0][e] = h2f(xv[e].x);
            acc[1][e] = h2f(xv[e].y);
            acc[2][e] = h2f(xv[e].z);
            acc[3][e] = h2f(xv[e].w);
        }

        __builtin_amdgcn_s_setprio(1);
        if (t > 0) {
            const unsigned short* hb = h_lds[rb];
#pragma unroll
            for (int kc = 0; kc < 4; ++kc) {
                const f16x8 a = *(const f16x8*)&hb[rd_off[kc]];
#pragma unroll
                for (int q = 0; q < 4; ++q)
                    acc[q] = mfma16h(a, bw[q][kc], acc[q]);
            }
        }
        __builtin_amdgcn_s_setprio(0);

        // land t+1's gather into xbuf[wb]; issue t+2's gather
        if (t + 1 < KST) {
            *(uint4*)&xbuf[wb][xb_wrA] = pa;    // waits vmcnt automatically
            *(uint4*)&xbuf[wb][xb_wrB] = pb;
            if (t + 2 < KST) {
                const unsigned oa = (unsigned)idx_lds[(t + 2) * 16 + 2 * w];
                const unsigned ob = (unsigned)idx_lds[(t + 2) * 16 + 2 * w + 1];
                pa = *(const uint4*)(xwr + oa + lane * 16);
                pb = *(const uint4*)(xwr + ob + lane * 16);
            }
        }

        // rcp-fused LSTM cell. Pre-activations arrive pre-scaled (i,f,o by
        // log2e; g by 2*log2e); cst = 2*log2e*c. Per element: 5 exp2 + 2 rcp.
        //   c' = c/Df + (1-Ag)/(Di*Dg) -> one rcp of Df*Di*Dg
        //   h  = (1-C2)/(Do*(1+C2))    -> one rcp
        unsigned short* nh = h_lds[wb];
#pragma unroll
        for (int e = 0; e < 4; ++e) {
            const float Ai = __builtin_amdgcn_exp2f(-acc[0][e]);
            const float Af = __builtin_amdgcn_exp2f(-acc[1][e]);
            const float Ag = __builtin_amdgcn_exp2f(-acc[2][e]);
            const float Ao = __builtin_amdgcn_exp2f(-acc[3][e]);
            const float Di = 1.0f + Ai, Df = 1.0f + Af;
            const float Dg = 1.0f + Ag, Do = 1.0f + Ao;
            const float DiDg = Di * Dg;
            const float P  = __builtin_fmaf(-TT, Ag, TT);          // TT*(1-Ag)
            const float num = __builtin_fmaf(cst[e], DiDg, P * Df);
            const float R1 = __builtin_amdgcn_rcpf(Df * DiDg);
            const float csn = num * R1;                            // 2*log2e*c'
            cst[e] = csn;
            const float C2 = __builtin_amdgcn_exp2f(-csn);
            const float R2 = __builtin_amdgcn_rcpf(Do * (1.0f + C2));
            nh[wr_off[e]] = f2h_bits((1.0f - C2) * R2);            // o*tanh(c')
        }
        barrier_lgkm();   // h(t) + xbuf(t+1) visible; vmcnt stays in flight
    }

    // ---- FC + leaky-relu: wave w -> out cols w*16+m, 16 nodes. h in buf[0].
    {
        const unsigned short* hb = h_lds[0];
        const float* fsr = fcs + (size_t)r * HD * HD;
        const float* fnr = fcn + (size_t)r * HD * HD;
        const int col = w * 16 + m;
        f32x4 oacc = f4splat(bias[r * HD + col]);
#pragma unroll
        for (int kc = 0; kc < 4; ++kc) {
            const f16x8 ax = load8h(x + (size_t)(n0 + m) * HD + kc * 32 + 8 * g);
            const f16x8 ah = *(const f16x8*)&hb[rd_off[kc]];
            const f16x8 bs = load8h(fsr + (size_t)col * HD + kc * 32 + 8 * g);
            const f16x8 bn = load8h(fnr + (size_t)col * HD + kc * 32 + 8 * g);
            oacc = mfma16h(ax, bs, oacc);
            oacc = mfma16h(ah, bn, oacc);
        }
#pragma unroll
        for (int e = 0; e < 4; ++e) {
            const int row = 4 * g + e;
            float v = oacc[e];
            v = v > 0.0f ? v : 0.01f * v;
            Xout[((size_t)(n0 + row) * NRELS + r) * HD + col] = v;
        }
    }
}

// ---------------------------------------------------------------------------
// attention: one wave per node; softmax over 3 relations, f32 throughout
// ---------------------------------------------------------------------------
__global__ __launch_bounds__(256) void attn_kernel(
    const float* __restrict__ X, const float* __restrict__ tc,
    float* __restrict__ out)
{
    const int wv = blockIdx.x * (blockDim.x >> 6) + (threadIdx.x >> 6);
    const int lane = threadIdx.x & 63;
    if (wv >= NN) return;
    const size_t nb = (size_t)wv;

    const float t0 = tc[nb * HD + lane];
    const float t1 = tc[nb * HD + 64 + lane];
    float x0[3], x1[3], sc[3];
#pragma unroll
    for (int r = 0; r < 3; ++r) {
        x0[r] = X[(nb * 3 + r) * HD + lane];
        x1[r] = X[(nb * 3 + r) * HD + 64 + lane];
        float p = x0[r] * t0 + x1[r] * t1;
#pragma unroll
        for (int off = 32; off >= 1; off >>= 1)
            p += __shfl_xor(p, off, 64);
        sc[r] = p;
    }
    const float mx = fmaxf(sc[0], fmaxf(sc[1], sc[2]));
    const float e0 = __expf(sc[0] - mx), e1 = __expf(sc[1] - mx), e2 = __expf(sc[2] - mx);
    const float inv = __builtin_amdgcn_rcpf(e0 + e1 + e2);
    const float a0 = e0 * inv, a1 = e1 * inv, a2 = e2 * inv;
    out[nb * HD + lane]      = a0 * x0[0] + a1 * x0[1] + a2 * x0[2];
    out[nb * HD + 64 + lane] = a0 * x1[0] + a1 * x1[1] + a2 * x1[2];
}

extern "C" void kernel_launch(void* const* d_in, const int* in_sizes, int n_in,
                              void* d_out, int out_size, void* d_ws, size_t ws_size,
                              hipStream_t stream)
{
    const float* x     = (const float*)d_in[0];
    const float* conn  = (const float*)d_in[1];
    const int*   nbr   = (const int*)d_in[2];
    const float* trans = (const float*)d_in[3];
    const float* Wih   = (const float*)d_in[4];
    const float* Whh   = (const float*)d_in[5];
    const float* blstm = (const float*)d_in[6];
    const float* fcs   = (const float*)d_in[7];
    const float* fcn   = (const float*)d_in[8];
    const float* bias  = (const float*)d_in[9];
    float* out = (float*)d_out;

    // ws carve: xW fp16 [3][N][512] | tc f32 [N][128] | X f32 [N][3][128]
    const size_t XW_B = (size_t)NRELS * NN * G4 * 2;   //  50.3 MB
    const size_t TC_B = (size_t)NN * HD * 4;           //   8.4 MB
    const size_t XO_B = (size_t)NN * NRELS * HD * 4;   //  25.2 MB
    if (ws_size < XW_B + TC_B + XO_B) return;          //  83.9 MB floor

    char* wsb = (char*)d_ws;
    unsigned short* xW = (unsigned short*)wsb;
    float*          tc = (float*)(wsb + XW_B);
    float*          Xo = (float*)(wsb + XW_B + TC_B);

    gemm_rt<512, 1><<<dim3(NN / 64, NRELS), 512, 0, stream>>>(x, Wih, blstm, (void*)xW);
    gemm_rt<128, 0><<<dim3(NN / 64, 1), 512, 0, stream>>>(conn, trans, nullptr, (void*)tc);
    lstm_kernel<<<dim3(NN / NPB, NRELS), 512, 0, stream>>>(x, nbr, Whh, fcs, fcn, bias, xW, Xo);
    attn_kernel<<<dim3(NN / 4), 256, 0, stream>>>(Xo, tc, out);
}